// Round 2
// baseline (872.916 us; speedup 1.0000x reference)
//
#include <hip/hip_runtime.h>
#include <hip/hip_bf16.h>
#include <stdint.h>

// Problem constants
#define P_TOTAL 4096
#define NSEQ    32
#define CDIM    512
#define NHEADS  8
#define DKH     64
#define NCLS    20

using bf16x8 = __attribute__((ext_vector_type(8))) __bf16;
using u16x8  = __attribute__((ext_vector_type(8))) unsigned short;
using u16x4  = __attribute__((ext_vector_type(4))) unsigned short;
using f32x4  = __attribute__((ext_vector_type(4))) float;

static_assert(sizeof(bf16x8) == 16, "bf16x8 must be 16B");

__device__ __forceinline__ unsigned short f2bf(float f) {
    uint32_t u = __builtin_bit_cast(uint32_t, f);
    u += 0x7fffu + ((u >> 16) & 1u);   // round-to-nearest-even
    return (unsigned short)(u >> 16);
}

// ---------------- K0a: Wq,Wk fp32 -> bf16 (ws) ----------------
__global__ void k_wconv(const float* __restrict__ Wq, const float* __restrict__ Wk,
                        unsigned short* __restrict__ Wbf) {
    int g = blockIdx.x * blockDim.x + threadIdx.x;          // 131072 float4s total
    const float* src = (g < 65536) ? (Wq + (size_t)g * 4) : (Wk + (size_t)(g - 65536) * 4);
    float4 v = *(const float4*)src;
    u16x4 o; o[0] = f2bf(v.x); o[1] = f2bf(v.y); o[2] = f2bf(v.z); o[3] = f2bf(v.w);
    *(u16x4*)(Wbf + (size_t)g * 4) = o;
}

// ---------------- K0b: x (N,C,P) fp32 -> xs (P,N,C) bf16 (ws) ----------------
__global__ void k_xpose(const float* __restrict__ x, unsigned short* __restrict__ xs) {
    __shared__ float tile[64][65];
    int b  = blockIdx.x;
    int pb = (b & 63) * 64;
    int cb = ((b >> 6) & 7) * 64;
    int n  = b >> 9;
    int t  = threadIdx.x;
#pragma unroll
    for (int pass = 0; pass < 4; ++pass) {
        int cc = pass * 16 + (t >> 4);
        int pp = (t & 15) * 4;
        float4 v = *(const float4*)(x + (((size_t)n * CDIM + cb + cc) << 12) + pb + pp);
        tile[cc][pp + 0] = v.x; tile[cc][pp + 1] = v.y;
        tile[cc][pp + 2] = v.z; tile[cc][pp + 3] = v.w;
    }
    __syncthreads();
#pragma unroll
    for (int pass = 0; pass < 2; ++pass) {
        int pr = pass * 32 + (t >> 3);
        int c8 = (t & 7) * 8;
        u16x8 o;
#pragma unroll
        for (int j = 0; j < 8; ++j) o[j] = f2bf(tile[c8 + j][pr]);
        *(u16x8*)(xs + (((size_t)(pb + pr) * NSEQ + n) << 9) + cb + c8) = o;
    }
}

// ---------------- K1: fused per-position attention ----------------
// LDS byte layout (total 160768 <= 163840):
//   xs   : 2 pos x [32][520] bf16            @ 0       (row 1040B, pos 33280B)
//   Q/K  : per wave: Q [32][72] bf16 + K     @ 66560   (row 144B, wave 9216B)
//   P    : per wave: [32][40] bf16           @ 140288  (row 80B, wave 2560B)
#define XS_ROW  1040
#define XS_POS  33280
#define QK_OFF  66560
#define QK_WAVE 9216
#define QROW    144
#define PB_OFF  140288
#define PB_WAVE 2560
#define PROW    80
#define SMEM_SZ 160768

template<bool FAST>
__global__ __launch_bounds__(512, 2)
void k_attn(const float* __restrict__ x,
            const unsigned short* __restrict__ Wbf,
            const unsigned short* __restrict__ xsbf,
            const float* __restrict__ Wq_f, const float* __restrict__ Wk_f,
            const float* __restrict__ bq, const float* __restrict__ bk,
            const float* __restrict__ Wl, const float* __restrict__ bl,
            float* __restrict__ out) {
    __shared__ __align__(16) char smem[SMEM_SZ];
    const int tid   = threadIdx.x;
    const int wave  = tid >> 6;          // 0..7 = head
    const int lane  = tid & 63;
    const int l15   = lane & 15;
    const int l4    = lane >> 4;
    const int p0    = blockIdx.x * 2;    // two positions per WG
    const int hbase = wave * DKH;

    // ---- stage xs for both positions into LDS (bf16, padded rows) ----
    if constexpr (FAST) {
        for (int i = tid; i < 4096; i += 512) {                 // 4096 x 16B chunks
            int pos = i >> 11;
            int rem = i & 2047;
            int n   = rem >> 6;
            int c8  = (rem & 63) << 3;
            u16x8 v = *(const u16x8*)(xsbf + (((size_t)(p0 + pos) * NSEQ + n) << 9) + c8);
            *(u16x8*)(smem + pos * XS_POS + n * XS_ROW + c8 * 2) = v;
        }
    } else {
        for (int e = tid; e < NSEQ * CDIM; e += 512) {
            int n = e >> 9, c = e & 511;
            float2 v = *(const float2*)(x + (((size_t)n * CDIM + c) << 12) + p0);
            *(unsigned short*)(smem + 0 * XS_POS + n * XS_ROW + c * 2) = f2bf(v.x);
            *(unsigned short*)(smem + 1 * XS_POS + n * XS_ROW + c * 2) = f2bf(v.y);
        }
    }
    __syncthreads();

    // ---- projections: Qt/Kt[d][n] = W_h @ xs^T, both positions ----
    f32x4 qacc[2][4][2], kacc[2][4][2];   // [pos][Mt(d)][Nt(n)]
#pragma unroll
    for (int a = 0; a < 2; ++a)
#pragma unroll
        for (int m = 0; m < 4; ++m)
#pragma unroll
            for (int c = 0; c < 2; ++c) {
                qacc[a][m][c] = f32x4{0.f, 0.f, 0.f, 0.f};
                kacc[a][m][c] = f32x4{0.f, 0.f, 0.f, 0.f};
            }

    for (int ks = 0; ks < 16; ++ks) {
        const int c0 = ks * 32 + l4 * 8;
        bf16x8 aq[4], ak[4];
#pragma unroll
        for (int mt = 0; mt < 4; ++mt) {
            const int row = hbase + mt * 16 + l15;
            if constexpr (FAST) {
                aq[mt] = __builtin_bit_cast(bf16x8, *(const u16x8*)(Wbf + (size_t)row * CDIM + c0));
                ak[mt] = __builtin_bit_cast(bf16x8, *(const u16x8*)(Wbf + 262144 + (size_t)row * CDIM + c0));
            } else {
                const float* pq = Wq_f + (size_t)row * CDIM + c0;
                const float* pk = Wk_f + (size_t)row * CDIM + c0;
                float4 q0 = *(const float4*)pq, q1 = *(const float4*)(pq + 4);
                float4 k0 = *(const float4*)pk, k1 = *(const float4*)(pk + 4);
                bf16x8 a, b;
                a[0] = (__bf16)q0.x; a[1] = (__bf16)q0.y; a[2] = (__bf16)q0.z; a[3] = (__bf16)q0.w;
                a[4] = (__bf16)q1.x; a[5] = (__bf16)q1.y; a[6] = (__bf16)q1.z; a[7] = (__bf16)q1.w;
                b[0] = (__bf16)k0.x; b[1] = (__bf16)k0.y; b[2] = (__bf16)k0.z; b[3] = (__bf16)k0.w;
                b[4] = (__bf16)k1.x; b[5] = (__bf16)k1.y; b[6] = (__bf16)k1.z; b[7] = (__bf16)k1.w;
                aq[mt] = a; ak[mt] = b;
            }
        }
#pragma unroll
        for (int pos = 0; pos < 2; ++pos) {
#pragma unroll
            for (int nt = 0; nt < 2; ++nt) {
                bf16x8 bfr = __builtin_bit_cast(bf16x8,
                    *(const u16x8*)(smem + pos * XS_POS + (nt * 16 + l15) * XS_ROW + c0 * 2));
#pragma unroll
                for (int mt = 0; mt < 4; ++mt) {
                    qacc[pos][mt][nt] = __builtin_amdgcn_mfma_f32_16x16x32_bf16(aq[mt], bfr, qacc[pos][mt][nt], 0, 0, 0);
                    kacc[pos][mt][nt] = __builtin_amdgcn_mfma_f32_16x16x32_bf16(ak[mt], bfr, kacc[pos][mt][nt], 0, 0, 0);
                }
            }
        }
    }

    char* Qb = smem + QK_OFF + wave * QK_WAVE;
    char* Kb = Qb + 4608;
    char* Pb = smem + PB_OFF + wave * PB_WAVE;

    for (int pos = 0; pos < 2; ++pos) {
        const int p = p0 + pos;

        // ---- stage Qt,Kt -> LDS as [n][d] bf16 (transposed write, +bias) ----
#pragma unroll
        for (int mt = 0; mt < 4; ++mt) {
#pragma unroll
            for (int nt = 0; nt < 2; ++nt) {
                u16x4 wq_, wk_;
#pragma unroll
                for (int r = 0; r < 4; ++r) {
                    const int dl = mt * 16 + l4 * 4 + r;
                    wq_[r] = f2bf(qacc[pos][mt][nt][r] + bq[hbase + dl]);
                    wk_[r] = f2bf(kacc[pos][mt][nt][r] + bk[hbase + dl]);
                }
                char* dst = Qb + (nt * 16 + l15) * QROW + (mt * 16 + l4 * 4) * 2;
                *(u16x4*)dst = wq_;
                *(u16x4*)(dst + 4608) = wk_;
            }
        }

        // ---- scores[n][m] = (1/8) * Q @ K^T ----
        f32x4 sc[2][2];
#pragma unroll
        for (int a = 0; a < 2; ++a)
#pragma unroll
            for (int b = 0; b < 2; ++b) sc[a][b] = f32x4{0.f, 0.f, 0.f, 0.f};
#pragma unroll
        for (int ks = 0; ks < 2; ++ks) {
            const int d0 = ks * 32 + l4 * 8;
            bf16x8 qa[2], kb[2];
#pragma unroll
            for (int nt = 0; nt < 2; ++nt)
                qa[nt] = __builtin_bit_cast(bf16x8, *(const u16x8*)(Qb + (nt * 16 + l15) * QROW + d0 * 2));
#pragma unroll
            for (int mt = 0; mt < 2; ++mt)
                kb[mt] = __builtin_bit_cast(bf16x8, *(const u16x8*)(Kb + (mt * 16 + l15) * QROW + d0 * 2));
#pragma unroll
            for (int nt = 0; nt < 2; ++nt)
#pragma unroll
                for (int mt = 0; mt < 2; ++mt)
                    sc[nt][mt] = __builtin_amdgcn_mfma_f32_16x16x32_bf16(qa[nt], kb[mt], sc[nt][mt], 0, 0, 0);
        }

        // ---- softmax over m (rows live in 16-lane groups), write P bf16 ----
#pragma unroll
        for (int nt = 0; nt < 2; ++nt) {
#pragma unroll
            for (int r = 0; r < 4; ++r) {
                float v0 = sc[nt][0][r] * 0.125f;
                float v1 = sc[nt][1][r] * 0.125f;
                float mx = fmaxf(v0, v1);
#pragma unroll
                for (int off = 8; off >= 1; off >>= 1) mx = fmaxf(mx, __shfl_xor(mx, off, 64));
                float e0 = __expf(v0 - mx), e1 = __expf(v1 - mx);
                float s = e0 + e1;
#pragma unroll
                for (int off = 8; off >= 1; off >>= 1) s += __shfl_xor(s, off, 64);
                float inv = 1.0f / s;
                const int row = nt * 16 + l4 * 4 + r;
                *(unsigned short*)(Pb + row * PROW + l15 * 2)        = f2bf(e0 * inv);
                *(unsigned short*)(Pb + row * PROW + (16 + l15) * 2) = f2bf(e1 * inv);
            }
        }

        // ---- PV: out[n][d] = P @ V, V straight from xs LDS ----
        f32x4 oacc[2][4];
#pragma unroll
        for (int a = 0; a < 2; ++a)
#pragma unroll
            for (int b = 0; b < 4; ++b) oacc[a][b] = f32x4{0.f, 0.f, 0.f, 0.f};
        bf16x8 pf[2];
#pragma unroll
        for (int nt = 0; nt < 2; ++nt)
            pf[nt] = __builtin_bit_cast(bf16x8, *(const u16x8*)(Pb + (nt * 16 + l15) * PROW + l4 * 16));
#pragma unroll
        for (int dt = 0; dt < 4; ++dt) {
            bf16x8 vf;
#pragma unroll
            for (int j = 0; j < 8; ++j) {
                unsigned short uv = *(const unsigned short*)(smem + pos * XS_POS +
                    (l4 * 8 + j) * XS_ROW + (hbase + dt * 16 + l15) * 2);
                vf[j] = __builtin_bit_cast(__bf16, uv);
            }
#pragma unroll
            for (int nt = 0; nt < 2; ++nt)
                oacc[nt][dt] = __builtin_amdgcn_mfma_f32_16x16x32_bf16(pf[nt], vf, oacc[nt][dt], 0, 0, 0);
        }

        // ---- stage out -> Kb (reuse) as [n][d] bf16 ----
#pragma unroll
        for (int nt = 0; nt < 2; ++nt)
#pragma unroll
            for (int dt = 0; dt < 4; ++dt)
#pragma unroll
                for (int r = 0; r < 4; ++r)
                    *(unsigned short*)(Kb + (nt * 16 + l4 * 4 + r) * QROW + (dt * 16 + l15) * 2)
                        = f2bf(oacc[nt][dt][r]);

        // ---- y_h[n][cls] = out_h @ Wl_h^T (cls padded to 32) ----
        f32x4 ya[2][2];
#pragma unroll
        for (int a = 0; a < 2; ++a)
#pragma unroll
            for (int b = 0; b < 2; ++b) ya[a][b] = f32x4{0.f, 0.f, 0.f, 0.f};
#pragma unroll
        for (int ks = 0; ks < 2; ++ks) {
            const int d0 = ks * 32 + l4 * 8;
            bf16x8 oa[2];
#pragma unroll
            for (int nt = 0; nt < 2; ++nt)
                oa[nt] = __builtin_bit_cast(bf16x8, *(const u16x8*)(Kb + (nt * 16 + l15) * QROW + d0 * 2));
            bf16x8 wb[2];
#pragma unroll
            for (int ct = 0; ct < 2; ++ct) {
                const int cls = ct * 16 + l15;
                bf16x8 w;
                if (cls < NCLS) {
                    const float* pw = Wl + (size_t)cls * CDIM + hbase + d0;
                    float4 w0 = *(const float4*)pw, w1 = *(const float4*)(pw + 4);
                    w[0] = (__bf16)w0.x; w[1] = (__bf16)w0.y; w[2] = (__bf16)w0.z; w[3] = (__bf16)w0.w;
                    w[4] = (__bf16)w1.x; w[5] = (__bf16)w1.y; w[6] = (__bf16)w1.z; w[7] = (__bf16)w1.w;
                } else {
#pragma unroll
                    for (int j = 0; j < 8; ++j) w[j] = (__bf16)0.0f;
                }
                wb[ct] = w;
            }
#pragma unroll
            for (int nt = 0; nt < 2; ++nt)
#pragma unroll
                for (int ct = 0; ct < 2; ++ct)
                    ya[nt][ct] = __builtin_amdgcn_mfma_f32_16x16x32_bf16(oa[nt], wb[ct], ya[nt][ct], 0, 0, 0);
        }

        // ---- per-wave partial y -> wave's Q area as fp32 [32][33] ----
        float* yl = (float*)Qb;
#pragma unroll
        for (int nt = 0; nt < 2; ++nt)
#pragma unroll
            for (int ct = 0; ct < 2; ++ct)
#pragma unroll
                for (int r = 0; r < 4; ++r)
                    yl[(nt * 16 + l4 * 4 + r) * 33 + ct * 16 + l15] = ya[nt][ct][r];
        __syncthreads();

        // ---- cross-wave reduce (+bl), then max over n, write output ----
        float* yf = (float*)(smem + PB_OFF);     // [32][20] fp32 in wave0's P area
        for (int e = tid; e < NSEQ * NCLS; e += 512) {
            const int n = e / NCLS, cls = e - n * NCLS;
            float s = bl[cls];
#pragma unroll
            for (int w2 = 0; w2 < 8; ++w2)
                s += ((const float*)(smem + QK_OFF + w2 * QK_WAVE))[n * 33 + cls];
            yf[e] = s;
        }
        __syncthreads();
        if (tid < NCLS) {
            float m = yf[tid];
#pragma unroll
            for (int n = 1; n < NSEQ; ++n) m = fmaxf(m, yf[n * NCLS + tid]);
            out[(size_t)p * NCLS + tid] = m;
        }
        __syncthreads();   // protect LDS reuse by next position
    }
}

extern "C" void kernel_launch(void* const* d_in, const int* in_sizes, int n_in,
                              void* d_out, int out_size, void* d_ws, size_t ws_size,
                              hipStream_t stream) {
    const float* x  = (const float*)d_in[0];
    const float* Wq = (const float*)d_in[1];
    const float* bq = (const float*)d_in[2];
    const float* Wk = (const float*)d_in[3];
    const float* bk = (const float*)d_in[4];
    const float* Wl = (const float*)d_in[5];
    const float* bl = (const float*)d_in[6];
    float* out = (float*)d_out;

    const size_t WBF_BYTES = (size_t)2 * 512 * 512 * 2;            // 1 MiB
    const size_t XS_BYTES  = (size_t)P_TOTAL * NSEQ * CDIM * 2;    // 128 MiB
    const bool fast = (d_ws != nullptr) && (ws_size >= WBF_BYTES + XS_BYTES);

    if (fast) {
        unsigned short* Wbf  = (unsigned short*)d_ws;
        unsigned short* xsbf = (unsigned short*)((char*)d_ws + WBF_BYTES);
        k_wconv<<<512, 256, 0, stream>>>(Wq, Wk, Wbf);
        k_xpose<<<16384, 256, 0, stream>>>(x, xsbf);
        k_attn<true><<<P_TOTAL / 2, 512, 0, stream>>>(x, Wbf, xsbf, Wq, Wk, bq, bk, Wl, bl, out);
    } else {
        k_attn<false><<<P_TOTAL / 2, 512, 0, stream>>>(x, nullptr, nullptr, Wq, Wk, bq, bk, Wl, bl, out);
    }
}

// Round 3
// 742.431 us; speedup vs baseline: 1.1758x; 1.1758x over previous
//
#include <hip/hip_runtime.h>
#include <hip/hip_bf16.h>
#include <stdint.h>

// Problem constants
#define P_TOTAL 4096
#define NSEQ    32
#define CDIM    512
#define NHEADS  8
#define DKH     64
#define NCLS    20

using bf16x8 = __attribute__((ext_vector_type(8))) __bf16;
using u16x8  = __attribute__((ext_vector_type(8))) unsigned short;
using u16x4  = __attribute__((ext_vector_type(4))) unsigned short;
using f32x4  = __attribute__((ext_vector_type(4))) float;

static_assert(sizeof(bf16x8) == 16, "bf16x8 must be 16B");

__device__ __forceinline__ unsigned short f2bf(float f) {
    uint32_t u = __builtin_bit_cast(uint32_t, f);
    u += 0x7fffu + ((u >> 16) & 1u);   // round-to-nearest-even
    return (unsigned short)(u >> 16);
}

// ---------------- K0a: Wq,Wk fp32 -> bf16 (ws) ----------------
__global__ void k_wconv(const float* __restrict__ Wq, const float* __restrict__ Wk,
                        unsigned short* __restrict__ Wbf) {
    int g = blockIdx.x * blockDim.x + threadIdx.x;          // 131072 float4s total
    const float* src = (g < 65536) ? (Wq + (size_t)g * 4) : (Wk + (size_t)(g - 65536) * 4);
    float4 v = *(const float4*)src;
    u16x4 o; o[0] = f2bf(v.x); o[1] = f2bf(v.y); o[2] = f2bf(v.z); o[3] = f2bf(v.w);
    *(u16x4*)(Wbf + (size_t)g * 4) = o;
}

// ---------------- K0b: x (N,C,P) fp32 -> xs (P,N,C) bf16 (ws) ----------------
// 4 n-values per block: grid = 64(p) * 8(c) * 8(n/4) = 4096 blocks
__global__ void k_xpose(const float* __restrict__ x, unsigned short* __restrict__ xs) {
    __shared__ float tile[64][65];
    int b  = blockIdx.x;
    int pb = (b & 63) * 64;
    int cb = ((b >> 6) & 7) * 64;
    int n0 = (b >> 9) * 4;
    int t  = threadIdx.x;
    for (int ni = 0; ni < 4; ++ni) {
        int n = n0 + ni;
        if (ni) __syncthreads();           // protect tile reuse
#pragma unroll
        for (int pass = 0; pass < 4; ++pass) {
            int cc = pass * 16 + (t >> 4);
            int pp = (t & 15) * 4;
            float4 v = *(const float4*)(x + (((size_t)n * CDIM + cb + cc) << 12) + pb + pp);
            tile[cc][pp + 0] = v.x; tile[cc][pp + 1] = v.y;
            tile[cc][pp + 2] = v.z; tile[cc][pp + 3] = v.w;
        }
        __syncthreads();
#pragma unroll
        for (int pass = 0; pass < 2; ++pass) {
            int pr = pass * 32 + (t >> 3);
            int c8 = (t & 7) * 8;
            u16x8 o;
#pragma unroll
            for (int j = 0; j < 8; ++j) o[j] = f2bf(tile[c8 + j][pr]);
            *(u16x8*)(xs + (((size_t)(pb + pr) * NSEQ + n) << 9) + cb + c8) = o;
        }
    }
}

// ---------------- K1: fused per-position attention ----------------
// LDS byte layout (total 160768 <= 163840):
//   xs   : 2 pos x [32][520] bf16            @ 0       (row 1040B, pos 33280B)
//   Q/K  : per wave: Q [32][72] bf16 + K     @ 66560   (row 144B, wave 9216B)
//   P    : per wave: [32][40] bf16           @ 140288  (row 80B, wave 2560B)
#define XS_ROW  1040
#define XS_POS  33280
#define QK_OFF  66560
#define QK_WAVE 9216
#define QROW    144
#define PB_OFF  140288
#define PB_WAVE 2560
#define PROW    80
#define SMEM_SZ 160768

template<bool FAST>
__global__ __launch_bounds__(512, 2)
void k_attn(const float* __restrict__ x,
            const unsigned short* __restrict__ Wbf,
            const unsigned short* __restrict__ xsbf,
            const float* __restrict__ Wq_f, const float* __restrict__ Wk_f,
            const float* __restrict__ bq, const float* __restrict__ bk,
            const float* __restrict__ Wl, const float* __restrict__ bl,
            float* __restrict__ out) {
    __shared__ __align__(16) char smem[SMEM_SZ];
    const int tid   = threadIdx.x;
    const int wave  = tid >> 6;          // 0..7 = head
    const int lane  = tid & 63;
    const int l15   = lane & 15;
    const int l4    = lane >> 4;
    const int p0    = blockIdx.x * 2;    // two positions per WG
    const int hbase = wave * DKH;

    // ---- stage xs for both positions into LDS (bf16, padded rows) ----
    if constexpr (FAST) {
        for (int i = tid; i < 4096; i += 512) {                 // 4096 x 16B chunks
            int pos = i >> 11;
            int rem = i & 2047;
            int n   = rem >> 6;
            int c8  = (rem & 63) << 3;
            u16x8 v = *(const u16x8*)(xsbf + (((size_t)(p0 + pos) * NSEQ + n) << 9) + c8);
            *(u16x8*)(smem + pos * XS_POS + n * XS_ROW + c8 * 2) = v;
        }
    } else {
        for (int e = tid; e < NSEQ * CDIM; e += 512) {
            int n = e >> 9, c = e & 511;
            float2 v = *(const float2*)(x + (((size_t)n * CDIM + c) << 12) + p0);
            *(unsigned short*)(smem + 0 * XS_POS + n * XS_ROW + c * 2) = f2bf(v.x);
            *(unsigned short*)(smem + 1 * XS_POS + n * XS_ROW + c * 2) = f2bf(v.y);
        }
    }
    __syncthreads();

    // ---- projections: Qt/Kt[d][n] = W_h @ xs^T, both positions ----
    f32x4 qacc[2][4][2], kacc[2][4][2];   // [pos][Mt(d)][Nt(n)] — ALL indexing static
#pragma unroll
    for (int a = 0; a < 2; ++a)
#pragma unroll
        for (int m = 0; m < 4; ++m)
#pragma unroll
            for (int c = 0; c < 2; ++c) {
                qacc[a][m][c] = f32x4{0.f, 0.f, 0.f, 0.f};
                kacc[a][m][c] = f32x4{0.f, 0.f, 0.f, 0.f};
            }

    for (int ks = 0; ks < 16; ++ks) {
        const int c0 = ks * 32 + l4 * 8;
        bf16x8 aq[4], ak[4];
#pragma unroll
        for (int mt = 0; mt < 4; ++mt) {
            const int row = hbase + mt * 16 + l15;
            if constexpr (FAST) {
                aq[mt] = __builtin_bit_cast(bf16x8, *(const u16x8*)(Wbf + (size_t)row * CDIM + c0));
                ak[mt] = __builtin_bit_cast(bf16x8, *(const u16x8*)(Wbf + 262144 + (size_t)row * CDIM + c0));
            } else {
                const float* pq = Wq_f + (size_t)row * CDIM + c0;
                const float* pk = Wk_f + (size_t)row * CDIM + c0;
                float4 q0 = *(const float4*)pq, q1 = *(const float4*)(pq + 4);
                float4 k0 = *(const float4*)pk, k1 = *(const float4*)(pk + 4);
                bf16x8 a, b;
                a[0] = (__bf16)q0.x; a[1] = (__bf16)q0.y; a[2] = (__bf16)q0.z; a[3] = (__bf16)q0.w;
                a[4] = (__bf16)q1.x; a[5] = (__bf16)q1.y; a[6] = (__bf16)q1.z; a[7] = (__bf16)q1.w;
                b[0] = (__bf16)k0.x; b[1] = (__bf16)k0.y; b[2] = (__bf16)k0.z; b[3] = (__bf16)k0.w;
                b[4] = (__bf16)k1.x; b[5] = (__bf16)k1.y; b[6] = (__bf16)k1.z; b[7] = (__bf16)k1.w;
                aq[mt] = a; ak[mt] = b;
            }
        }
#pragma unroll
        for (int pos = 0; pos < 2; ++pos) {
#pragma unroll
            for (int nt = 0; nt < 2; ++nt) {
                bf16x8 bfr = __builtin_bit_cast(bf16x8,
                    *(const u16x8*)(smem + pos * XS_POS + (nt * 16 + l15) * XS_ROW + c0 * 2));
#pragma unroll
                for (int mt = 0; mt < 4; ++mt) {
                    qacc[pos][mt][nt] = __builtin_amdgcn_mfma_f32_16x16x32_bf16(aq[mt], bfr, qacc[pos][mt][nt], 0, 0, 0);
                    kacc[pos][mt][nt] = __builtin_amdgcn_mfma_f32_16x16x32_bf16(ak[mt], bfr, kacc[pos][mt][nt], 0, 0, 0);
                }
            }
        }
    }

    char* Qb = smem + QK_OFF + wave * QK_WAVE;
    char* Kb = Qb + 4608;
    char* Pb = smem + PB_OFF + wave * PB_WAVE;

    // NOTE: #pragma unroll is REQUIRED here — runtime `pos` indexing of
    // qacc/kacc sends the 128-VGPR accumulator block to scratch (rule #20;
    // round-2 counters: WRITE_SIZE 590 MB of spill traffic, VGPR=108).
#pragma unroll
    for (int pos = 0; pos < 2; ++pos) {
        const int p = p0 + pos;

        // ---- stage Qt,Kt -> LDS as [n][d] bf16 (transposed write, +bias) ----
#pragma unroll
        for (int mt = 0; mt < 4; ++mt) {
#pragma unroll
            for (int nt = 0; nt < 2; ++nt) {
                u16x4 wq_, wk_;
#pragma unroll
                for (int r = 0; r < 4; ++r) {
                    const int dl = mt * 16 + l4 * 4 + r;
                    wq_[r] = f2bf(qacc[pos][mt][nt][r] + bq[hbase + dl]);
                    wk_[r] = f2bf(kacc[pos][mt][nt][r] + bk[hbase + dl]);
                }
                char* dst = Qb + (nt * 16 + l15) * QROW + (mt * 16 + l4 * 4) * 2;
                *(u16x4*)dst = wq_;
                *(u16x4*)(dst + 4608) = wk_;
            }
        }

        // ---- scores[n][m] = (1/8) * Q @ K^T ----
        f32x4 sc[2][2];
#pragma unroll
        for (int a = 0; a < 2; ++a)
#pragma unroll
            for (int b = 0; b < 2; ++b) sc[a][b] = f32x4{0.f, 0.f, 0.f, 0.f};
#pragma unroll
        for (int ks = 0; ks < 2; ++ks) {
            const int d0 = ks * 32 + l4 * 8;
            bf16x8 qa[2], kb[2];
#pragma unroll
            for (int nt = 0; nt < 2; ++nt)
                qa[nt] = __builtin_bit_cast(bf16x8, *(const u16x8*)(Qb + (nt * 16 + l15) * QROW + d0 * 2));
#pragma unroll
            for (int mt = 0; mt < 2; ++mt)
                kb[mt] = __builtin_bit_cast(bf16x8, *(const u16x8*)(Kb + (mt * 16 + l15) * QROW + d0 * 2));
#pragma unroll
            for (int nt = 0; nt < 2; ++nt)
#pragma unroll
                for (int mt = 0; mt < 2; ++mt)
                    sc[nt][mt] = __builtin_amdgcn_mfma_f32_16x16x32_bf16(qa[nt], kb[mt], sc[nt][mt], 0, 0, 0);
        }

        // ---- softmax over m (rows live in 16-lane groups), write P bf16 ----
#pragma unroll
        for (int nt = 0; nt < 2; ++nt) {
#pragma unroll
            for (int r = 0; r < 4; ++r) {
                float v0 = sc[nt][0][r] * 0.125f;
                float v1 = sc[nt][1][r] * 0.125f;
                float mx = fmaxf(v0, v1);
#pragma unroll
                for (int off = 8; off >= 1; off >>= 1) mx = fmaxf(mx, __shfl_xor(mx, off, 64));
                float e0 = __expf(v0 - mx), e1 = __expf(v1 - mx);
                float s = e0 + e1;
#pragma unroll
                for (int off = 8; off >= 1; off >>= 1) s += __shfl_xor(s, off, 64);
                float inv = 1.0f / s;
                const int row = nt * 16 + l4 * 4 + r;
                *(unsigned short*)(Pb + row * PROW + l15 * 2)        = f2bf(e0 * inv);
                *(unsigned short*)(Pb + row * PROW + (16 + l15) * 2) = f2bf(e1 * inv);
            }
        }

        // ---- PV: out[n][d] = P @ V, V straight from xs LDS ----
        f32x4 oacc[2][4];
#pragma unroll
        for (int a = 0; a < 2; ++a)
#pragma unroll
            for (int b = 0; b < 4; ++b) oacc[a][b] = f32x4{0.f, 0.f, 0.f, 0.f};
        bf16x8 pf[2];
#pragma unroll
        for (int nt = 0; nt < 2; ++nt)
            pf[nt] = __builtin_bit_cast(bf16x8, *(const u16x8*)(Pb + (nt * 16 + l15) * PROW + l4 * 16));
#pragma unroll
        for (int dt = 0; dt < 4; ++dt) {
            bf16x8 vf;
#pragma unroll
            for (int j = 0; j < 8; ++j) {
                unsigned short uv = *(const unsigned short*)(smem + pos * XS_POS +
                    (l4 * 8 + j) * XS_ROW + (hbase + dt * 16 + l15) * 2);
                vf[j] = __builtin_bit_cast(__bf16, uv);
            }
#pragma unroll
            for (int nt = 0; nt < 2; ++nt)
                oacc[nt][dt] = __builtin_amdgcn_mfma_f32_16x16x32_bf16(pf[nt], vf, oacc[nt][dt], 0, 0, 0);
        }

        // ---- stage out -> Kb (reuse) as [n][d] bf16 ----
#pragma unroll
        for (int nt = 0; nt < 2; ++nt)
#pragma unroll
            for (int dt = 0; dt < 4; ++dt)
#pragma unroll
                for (int r = 0; r < 4; ++r)
                    *(unsigned short*)(Kb + (nt * 16 + l4 * 4 + r) * QROW + (dt * 16 + l15) * 2)
                        = f2bf(oacc[nt][dt][r]);

        // ---- y_h[n][cls] = out_h @ Wl_h^T (cls padded to 32) ----
        f32x4 ya[2][2];
#pragma unroll
        for (int a = 0; a < 2; ++a)
#pragma unroll
            for (int b = 0; b < 2; ++b) ya[a][b] = f32x4{0.f, 0.f, 0.f, 0.f};
#pragma unroll
        for (int ks = 0; ks < 2; ++ks) {
            const int d0 = ks * 32 + l4 * 8;
            bf16x8 oa[2];
#pragma unroll
            for (int nt = 0; nt < 2; ++nt)
                oa[nt] = __builtin_bit_cast(bf16x8, *(const u16x8*)(Kb + (nt * 16 + l15) * QROW + d0 * 2));
            bf16x8 wb[2];
#pragma unroll
            for (int ct = 0; ct < 2; ++ct) {
                const int cls = ct * 16 + l15;
                bf16x8 w;
                if (cls < NCLS) {
                    const float* pw = Wl + (size_t)cls * CDIM + hbase + d0;
                    float4 w0 = *(const float4*)pw, w1 = *(const float4*)(pw + 4);
                    w[0] = (__bf16)w0.x; w[1] = (__bf16)w0.y; w[2] = (__bf16)w0.z; w[3] = (__bf16)w0.w;
                    w[4] = (__bf16)w1.x; w[5] = (__bf16)w1.y; w[6] = (__bf16)w1.z; w[7] = (__bf16)w1.w;
                } else {
#pragma unroll
                    for (int j = 0; j < 8; ++j) w[j] = (__bf16)0.0f;
                }
                wb[ct] = w;
            }
#pragma unroll
            for (int nt = 0; nt < 2; ++nt)
#pragma unroll
                for (int ct = 0; ct < 2; ++ct)
                    ya[nt][ct] = __builtin_amdgcn_mfma_f32_16x16x32_bf16(oa[nt], wb[ct], ya[nt][ct], 0, 0, 0);
        }

        // ---- per-wave partial y -> wave's Q area as fp32 [32][33] ----
        float* yl = (float*)Qb;
#pragma unroll
        for (int nt = 0; nt < 2; ++nt)
#pragma unroll
            for (int ct = 0; ct < 2; ++ct)
#pragma unroll
                for (int r = 0; r < 4; ++r)
                    yl[(nt * 16 + l4 * 4 + r) * 33 + ct * 16 + l15] = ya[nt][ct][r];
        __syncthreads();

        // ---- cross-wave reduce (+bl), then max over n, write output ----
        float* yf = (float*)(smem + PB_OFF);     // [32][20] fp32 in wave0's P area
        for (int e = tid; e < NSEQ * NCLS; e += 512) {
            const int n = e / NCLS, cls = e - n * NCLS;
            float s = bl[cls];
#pragma unroll
            for (int w2 = 0; w2 < 8; ++w2)
                s += ((const float*)(smem + QK_OFF + w2 * QK_WAVE))[n * 33 + cls];
            yf[e] = s;
        }
        __syncthreads();
        if (tid < NCLS) {
            float m = yf[tid];
#pragma unroll
            for (int n = 1; n < NSEQ; ++n) m = fmaxf(m, yf[n * NCLS + tid]);
            out[(size_t)p * NCLS + tid] = m;
        }
        __syncthreads();   // protect LDS reuse by next position
    }
}

extern "C" void kernel_launch(void* const* d_in, const int* in_sizes, int n_in,
                              void* d_out, int out_size, void* d_ws, size_t ws_size,
                              hipStream_t stream) {
    const float* x  = (const float*)d_in[0];
    const float* Wq = (const float*)d_in[1];
    const float* bq = (const float*)d_in[2];
    const float* Wk = (const float*)d_in[3];
    const float* bk = (const float*)d_in[4];
    const float* Wl = (const float*)d_in[5];
    const float* bl = (const float*)d_in[6];
    float* out = (float*)d_out;

    const size_t WBF_BYTES = (size_t)2 * 512 * 512 * 2;            // 1 MiB
    const size_t XS_BYTES  = (size_t)P_TOTAL * NSEQ * CDIM * 2;    // 128 MiB
    const bool fast = (d_ws != nullptr) && (ws_size >= WBF_BYTES + XS_BYTES);

    if (fast) {
        unsigned short* Wbf  = (unsigned short*)d_ws;
        unsigned short* xsbf = (unsigned short*)((char*)d_ws + WBF_BYTES);
        k_wconv<<<512, 256, 0, stream>>>(Wq, Wk, Wbf);
        k_xpose<<<4096, 256, 0, stream>>>(x, xsbf);
        k_attn<true><<<P_TOTAL / 2, 512, 0, stream>>>(x, Wbf, xsbf, Wq, Wk, bq, bk, Wl, bl, out);
    } else {
        k_attn<false><<<P_TOTAL / 2, 512, 0, stream>>>(x, nullptr, nullptr, Wq, Wk, bq, bk, Wl, bl, out);
    }
}

// Round 4
// 720.870 us; speedup vs baseline: 1.2109x; 1.0299x over previous
//
#include <hip/hip_runtime.h>
#include <hip/hip_bf16.h>
#include <stdint.h>

// Problem constants
#define P_TOTAL 4096
#define NSEQ    32
#define CDIM    512
#define NHEADS  8
#define DKH     64
#define NCLS    20

using bf16x8 = __attribute__((ext_vector_type(8))) __bf16;
using u16x8  = __attribute__((ext_vector_type(8))) unsigned short;
using u16x4  = __attribute__((ext_vector_type(4))) unsigned short;
using f32x4  = __attribute__((ext_vector_type(4))) float;
using u32x2  = __attribute__((ext_vector_type(2))) unsigned int;
using u32x4  = __attribute__((ext_vector_type(4))) unsigned int;

static_assert(sizeof(bf16x8) == 16, "bf16x8 must be 16B");

__device__ __forceinline__ unsigned short f2bf(float f) {
    uint32_t u = __builtin_bit_cast(uint32_t, f);
    u += 0x7fffu + ((u >> 16) & 1u);   // round-to-nearest-even
    return (unsigned short)(u >> 16);
}
__device__ __forceinline__ unsigned int pk2bf(float a, float b) {
    return (unsigned int)f2bf(a) | ((unsigned int)f2bf(b) << 16);
}

// ---------------- K0a: Wq,Wk fp32 -> bf16 (ws) ----------------
__global__ void k_wconv(const float* __restrict__ Wq, const float* __restrict__ Wk,
                        unsigned short* __restrict__ Wbf) {
    int g = blockIdx.x * blockDim.x + threadIdx.x;          // 131072 float4s total
    const float* src = (g < 65536) ? (Wq + (size_t)g * 4) : (Wk + (size_t)(g - 65536) * 4);
    float4 v = *(const float4*)src;
    u16x4 o; o[0] = f2bf(v.x); o[1] = f2bf(v.y); o[2] = f2bf(v.z); o[3] = f2bf(v.w);
    *(u16x4*)(Wbf + (size_t)g * 4) = o;
}

// ---------------- K0b: x (N,C,P) fp32 -> xs (P,N,C) bf16 (ws) ----------------
__global__ void k_xpose(const float* __restrict__ x, unsigned short* __restrict__ xs) {
    __shared__ float tile[64][65];
    int b  = blockIdx.x;
    int pb = (b & 63) * 64;
    int cb = ((b >> 6) & 7) * 64;
    int n0 = (b >> 9) * 4;
    int t  = threadIdx.x;
    for (int ni = 0; ni < 4; ++ni) {
        int n = n0 + ni;
        if (ni) __syncthreads();
#pragma unroll
        for (int pass = 0; pass < 4; ++pass) {
            int cc = pass * 16 + (t >> 4);
            int pp = (t & 15) * 4;
            float4 v = *(const float4*)(x + (((size_t)n * CDIM + cb + cc) << 12) + pb + pp);
            tile[cc][pp + 0] = v.x; tile[cc][pp + 1] = v.y;
            tile[cc][pp + 2] = v.z; tile[cc][pp + 3] = v.w;
        }
        __syncthreads();
#pragma unroll
        for (int pass = 0; pass < 2; ++pass) {
            int pr = pass * 32 + (t >> 3);
            int c8 = (t & 7) * 8;
            u16x8 o;
#pragma unroll
            for (int j = 0; j < 8; ++j) o[j] = f2bf(tile[c8 + j][pr]);
            *(u16x8*)(xs + (((size_t)(pb + pr) * NSEQ + n) << 9) + cb + c8) = o;
        }
    }
}

// ---------------- K1: fused per-position attention ----------------
// LDS byte layout (total 156672 <= 163840):
//   xs   : 2 pos x [32][520] bf16            @ 0       (row 1040B, pos 33280B)
//   Q/K  : per wave: Q [32][72] bf16 + K     @ 66560   (row 144B, wave 9216B)
//   P    : per wave: 2 nt x 64 lanes x 16B   @ 140288  (wave 2048B)
#define XS_ROW  1040
#define XS_POS  33280
#define QK_OFF  66560
#define QK_WAVE 9216
#define QROW    144
#define PB_OFF  140288
#define PB_WAVE 2048
#define SMEM_SZ 156672

template<bool FAST>
__global__ __launch_bounds__(512, 2)
void k_attn(const float* __restrict__ x,
            const unsigned short* __restrict__ Wbf,
            const unsigned short* __restrict__ xsbf,
            const float* __restrict__ Wq_f, const float* __restrict__ Wk_f,
            const float* __restrict__ bq, const float* __restrict__ bk,
            const float* __restrict__ Wl, const float* __restrict__ bl,
            float* __restrict__ out) {
    __shared__ __align__(16) char smem[SMEM_SZ];
    const int tid   = threadIdx.x;
    const int wave  = tid >> 6;          // 0..7 = head
    const int lane  = tid & 63;
    const int l15   = lane & 15;
    const int l4    = lane >> 4;
    const int p0    = blockIdx.x * 2;    // two positions per WG
    const int hbase = wave * DKH;

    // ---- stage xs for both positions into LDS (bf16, padded rows) ----
    if constexpr (FAST) {
        for (int i = tid; i < 4096; i += 512) {                 // 4096 x 16B chunks
            int pos = i >> 11;
            int rem = i & 2047;
            int n   = rem >> 6;
            int c8  = (rem & 63) << 3;
            u16x8 v = *(const u16x8*)(xsbf + (((size_t)(p0 + pos) * NSEQ + n) << 9) + c8);
            *(u16x8*)(smem + pos * XS_POS + n * XS_ROW + c8 * 2) = v;
        }
    } else {
        for (int e = tid; e < NSEQ * CDIM; e += 512) {
            int n = e >> 9, c = e & 511;
            float2 v = *(const float2*)(x + (((size_t)n * CDIM + c) << 12) + p0);
            *(unsigned short*)(smem + 0 * XS_POS + n * XS_ROW + c * 2) = f2bf(v.x);
            *(unsigned short*)(smem + 1 * XS_POS + n * XS_ROW + c * 2) = f2bf(v.y);
        }
    }
    __syncthreads();

    // ---- projections: Qt/Kt[d][n] = W_h @ xs^T, both positions ----
    f32x4 qacc[2][4][2], kacc[2][4][2];   // [pos][Mt(d)][Nt(n)] — ALL indexing static
#pragma unroll
    for (int a = 0; a < 2; ++a)
#pragma unroll
        for (int m = 0; m < 4; ++m)
#pragma unroll
            for (int c = 0; c < 2; ++c) {
                qacc[a][m][c] = f32x4{0.f, 0.f, 0.f, 0.f};
                kacc[a][m][c] = f32x4{0.f, 0.f, 0.f, 0.f};
            }

    for (int ks = 0; ks < 16; ++ks) {
        const int c0 = ks * 32 + l4 * 8;
        bf16x8 aq[4], ak[4];
#pragma unroll
        for (int mt = 0; mt < 4; ++mt) {
            const int row = hbase + mt * 16 + l15;
            if constexpr (FAST) {
                aq[mt] = __builtin_bit_cast(bf16x8, *(const u16x8*)(Wbf + (size_t)row * CDIM + c0));
                ak[mt] = __builtin_bit_cast(bf16x8, *(const u16x8*)(Wbf + 262144 + (size_t)row * CDIM + c0));
            } else {
                const float* pq = Wq_f + (size_t)row * CDIM + c0;
                const float* pk = Wk_f + (size_t)row * CDIM + c0;
                float4 q0 = *(const float4*)pq, q1 = *(const float4*)(pq + 4);
                float4 k0 = *(const float4*)pk, k1 = *(const float4*)(pk + 4);
                bf16x8 a, b;
                a[0] = (__bf16)q0.x; a[1] = (__bf16)q0.y; a[2] = (__bf16)q0.z; a[3] = (__bf16)q0.w;
                a[4] = (__bf16)q1.x; a[5] = (__bf16)q1.y; a[6] = (__bf16)q1.z; a[7] = (__bf16)q1.w;
                b[0] = (__bf16)k0.x; b[1] = (__bf16)k0.y; b[2] = (__bf16)k0.z; b[3] = (__bf16)k0.w;
                b[4] = (__bf16)k1.x; b[5] = (__bf16)k1.y; b[6] = (__bf16)k1.z; b[7] = (__bf16)k1.w;
                aq[mt] = a; ak[mt] = b;
            }
        }
#pragma unroll
        for (int pos = 0; pos < 2; ++pos) {
#pragma unroll
            for (int nt = 0; nt < 2; ++nt) {
                bf16x8 bfr = __builtin_bit_cast(bf16x8,
                    *(const u16x8*)(smem + pos * XS_POS + (nt * 16 + l15) * XS_ROW + c0 * 2));
#pragma unroll
                for (int mt = 0; mt < 4; ++mt) {
                    qacc[pos][mt][nt] = __builtin_amdgcn_mfma_f32_16x16x32_bf16(aq[mt], bfr, qacc[pos][mt][nt], 0, 0, 0);
                    kacc[pos][mt][nt] = __builtin_amdgcn_mfma_f32_16x16x32_bf16(ak[mt], bfr, kacc[pos][mt][nt], 0, 0, 0);
                }
            }
        }
    }

    char* Qb = smem + QK_OFF + wave * QK_WAVE;
    char* Kb = Qb + 4608;
    char* Pb = smem + PB_OFF + wave * PB_WAVE;

    // NOTE: #pragma unroll REQUIRED — runtime `pos` indexing of qacc/kacc
    // spills the accumulator block to scratch (rule #20; round-2 counters).
#pragma unroll
    for (int pos = 0; pos < 2; ++pos) {
        const int p = p0 + pos;

        // ---- stage Qt,Kt -> LDS as [n][d] bf16 (transposed write, +bias) ----
#pragma unroll
        for (int mt = 0; mt < 4; ++mt) {
#pragma unroll
            for (int nt = 0; nt < 2; ++nt) {
                u16x4 wq_, wk_;
#pragma unroll
                for (int r = 0; r < 4; ++r) {
                    const int dl = mt * 16 + l4 * 4 + r;
                    wq_[r] = f2bf(qacc[pos][mt][nt][r] + bq[hbase + dl]);
                    wk_[r] = f2bf(kacc[pos][mt][nt][r] + bk[hbase + dl]);
                }
                char* dst = Qb + (nt * 16 + l15) * QROW + (mt * 16 + l4 * 4) * 2;
                *(u16x4*)dst = wq_;
                *(u16x4*)(dst + 4608) = wk_;
            }
        }

        // ---- scores TRANSPOSED: scT[mt][nt] = K @ Q^T (row=m, col=n) ----
        // Same LDS reads as before; operand roles swapped so softmax's m-axis
        // lands in registers (8 vals/lane) instead of across l15 lanes.
        f32x4 scT[2][2];
#pragma unroll
        for (int a = 0; a < 2; ++a)
#pragma unroll
            for (int b = 0; b < 2; ++b) scT[a][b] = f32x4{0.f, 0.f, 0.f, 0.f};
#pragma unroll
        for (int ks = 0; ks < 2; ++ks) {
            const int d0 = ks * 32 + l4 * 8;
            bf16x8 qa[2], kb[2];
#pragma unroll
            for (int nt = 0; nt < 2; ++nt)
                qa[nt] = __builtin_bit_cast(bf16x8, *(const u16x8*)(Qb + (nt * 16 + l15) * QROW + d0 * 2));
#pragma unroll
            for (int mt = 0; mt < 2; ++mt)
                kb[mt] = __builtin_bit_cast(bf16x8, *(const u16x8*)(Kb + (mt * 16 + l15) * QROW + d0 * 2));
#pragma unroll
            for (int mt = 0; mt < 2; ++mt)
#pragma unroll
                for (int nt = 0; nt < 2; ++nt)
                    scT[mt][nt] = __builtin_amdgcn_mfma_f32_16x16x32_bf16(kb[mt], qa[nt], scT[mt][nt], 0, 0, 0);
        }

        // ---- softmax over m: in-reg tree (8 vals) + xor16 + xor32 ----
        // Lane (s=l4, n=l15): holds P[m = mt*16 + s*4 + r][n] for query n.
        // Pack to 4 u32 words W[mt*2+rp] = (p[mt][2rp], p[mt][2rp+1]); one
        // b128 write; A-frag for PV re-read as two b64 (mapping verified:
        // a[j] = P[n][g*8+j] for reading lane-group g).
#pragma unroll
        for (int nt = 0; nt < 2; ++nt) {
            float v[8];
#pragma unroll
            for (int mt = 0; mt < 2; ++mt)
#pragma unroll
                for (int r = 0; r < 4; ++r)
                    v[mt * 4 + r] = scT[mt][nt][r] * 0.125f;
            float mx = v[0];
#pragma unroll
            for (int i = 1; i < 8; ++i) mx = fmaxf(mx, v[i]);
            mx = fmaxf(mx, __shfl_xor(mx, 16, 64));
            mx = fmaxf(mx, __shfl_xor(mx, 32, 64));
            float e[8], s = 0.f;
#pragma unroll
            for (int i = 0; i < 8; ++i) { e[i] = __expf(v[i] - mx); s += e[i]; }
            s += __shfl_xor(s, 16, 64);
            s += __shfl_xor(s, 32, 64);
            float inv = 1.0f / s;
            u32x4 W;
#pragma unroll
            for (int mt = 0; mt < 2; ++mt)
#pragma unroll
                for (int rp = 0; rp < 2; ++rp)
                    W[mt * 2 + rp] = pk2bf(e[mt * 4 + 2 * rp] * inv, e[mt * 4 + 2 * rp + 1] * inv);
            *(u32x4*)(Pb + nt * 1024 + (l4 * 16 + l15) * 16) = W;
        }

        // ---- PV: out[n][d] = P @ V, V straight from xs LDS ----
        bf16x8 pf[2];
#pragma unroll
        for (int nt = 0; nt < 2; ++nt) {
            const int sA = 2 * (l4 & 1);        // src lane-group for words 0,1
            const int off = (l4 >> 1) * 8;      // byte offset selecting mt
            u32x2 lo = *(const u32x2*)(Pb + nt * 1024 + (sA * 16 + l15) * 16 + off);
            u32x2 hi = *(const u32x2*)(Pb + nt * 1024 + ((sA + 1) * 16 + l15) * 16 + off);
            u32x4 w4; w4[0] = lo[0]; w4[1] = lo[1]; w4[2] = hi[0]; w4[3] = hi[1];
            pf[nt] = __builtin_bit_cast(bf16x8, w4);
        }
        f32x4 oacc[2][4];
#pragma unroll
        for (int a = 0; a < 2; ++a)
#pragma unroll
            for (int b = 0; b < 4; ++b) oacc[a][b] = f32x4{0.f, 0.f, 0.f, 0.f};
#pragma unroll
        for (int dt = 0; dt < 4; ++dt) {
            bf16x8 vf;
#pragma unroll
            for (int j = 0; j < 8; ++j) {
                unsigned short uv = *(const unsigned short*)(smem + pos * XS_POS +
                    (l4 * 8 + j) * XS_ROW + (hbase + dt * 16 + l15) * 2);
                vf[j] = __builtin_bit_cast(__bf16, uv);
            }
#pragma unroll
            for (int nt = 0; nt < 2; ++nt)
                oacc[nt][dt] = __builtin_amdgcn_mfma_f32_16x16x32_bf16(pf[nt], vf, oacc[nt][dt], 0, 0, 0);
        }

        // ---- stage out -> Kb (reuse) as [n][d] bf16 ----
#pragma unroll
        for (int nt = 0; nt < 2; ++nt)
#pragma unroll
            for (int dt = 0; dt < 4; ++dt)
#pragma unroll
                for (int r = 0; r < 4; ++r)
                    *(unsigned short*)(Kb + (nt * 16 + l4 * 4 + r) * QROW + (dt * 16 + l15) * 2)
                        = f2bf(oacc[nt][dt][r]);

        // ---- y_h[n][cls] = out_h @ Wl_h^T (cls padded to 32) ----
        f32x4 ya[2][2];
#pragma unroll
        for (int a = 0; a < 2; ++a)
#pragma unroll
            for (int b = 0; b < 2; ++b) ya[a][b] = f32x4{0.f, 0.f, 0.f, 0.f};
#pragma unroll
        for (int ks = 0; ks < 2; ++ks) {
            const int d0 = ks * 32 + l4 * 8;
            bf16x8 oa[2];
#pragma unroll
            for (int nt = 0; nt < 2; ++nt)
                oa[nt] = __builtin_bit_cast(bf16x8, *(const u16x8*)(Kb + (nt * 16 + l15) * QROW + d0 * 2));
            bf16x8 wb[2];
#pragma unroll
            for (int ct = 0; ct < 2; ++ct) {
                const int cls = ct * 16 + l15;
                bf16x8 w;
                if (cls < NCLS) {
                    const float* pw = Wl + (size_t)cls * CDIM + hbase + d0;
                    float4 w0 = *(const float4*)pw, w1 = *(const float4*)(pw + 4);
                    w[0] = (__bf16)w0.x; w[1] = (__bf16)w0.y; w[2] = (__bf16)w0.z; w[3] = (__bf16)w0.w;
                    w[4] = (__bf16)w1.x; w[5] = (__bf16)w1.y; w[6] = (__bf16)w1.z; w[7] = (__bf16)w1.w;
                } else {
#pragma unroll
                    for (int j = 0; j < 8; ++j) w[j] = (__bf16)0.0f;
                }
                wb[ct] = w;
            }
#pragma unroll
            for (int nt = 0; nt < 2; ++nt)
#pragma unroll
                for (int ct = 0; ct < 2; ++ct)
                    ya[nt][ct] = __builtin_amdgcn_mfma_f32_16x16x32_bf16(oa[nt], wb[ct], ya[nt][ct], 0, 0, 0);
        }

        // ---- per-wave partial y -> wave's Q area as fp32 [32][33] ----
        float* yl = (float*)Qb;
#pragma unroll
        for (int nt = 0; nt < 2; ++nt)
#pragma unroll
            for (int ct = 0; ct < 2; ++ct)
#pragma unroll
                for (int r = 0; r < 4; ++r)
                    yl[(nt * 16 + l4 * 4 + r) * 33 + ct * 16 + l15] = ya[nt][ct][r];
        __syncthreads();

        // ---- cross-wave reduce (+bl), then max over n, write output ----
        float* yf = (float*)(smem + PB_OFF);     // [32][20] fp32 over P area (dead)
        for (int e = tid; e < NSEQ * NCLS; e += 512) {
            const int n = e / NCLS, cls = e - n * NCLS;
            float s = bl[cls];
#pragma unroll
            for (int w2 = 0; w2 < 8; ++w2)
                s += ((const float*)(smem + QK_OFF + w2 * QK_WAVE))[n * 33 + cls];
            yf[e] = s;
        }
        __syncthreads();
        if (tid < NCLS) {
            float m = yf[tid];
#pragma unroll
            for (int n = 1; n < NSEQ; ++n) m = fmaxf(m, yf[n * NCLS + tid]);
            out[(size_t)p * NCLS + tid] = m;
        }
        __syncthreads();   // protect LDS reuse by next position
    }
}

extern "C" void kernel_launch(void* const* d_in, const int* in_sizes, int n_in,
                              void* d_out, int out_size, void* d_ws, size_t ws_size,
                              hipStream_t stream) {
    const float* x  = (const float*)d_in[0];
    const float* Wq = (const float*)d_in[1];
    const float* bq = (const float*)d_in[2];
    const float* Wk = (const float*)d_in[3];
    const float* bk = (const float*)d_in[4];
    const float* Wl = (const float*)d_in[5];
    const float* bl = (const float*)d_in[6];
    float* out = (float*)d_out;

    const size_t WBF_BYTES = (size_t)2 * 512 * 512 * 2;            // 1 MiB
    const size_t XS_BYTES  = (size_t)P_TOTAL * NSEQ * CDIM * 2;    // 128 MiB
    const bool fast = (d_ws != nullptr) && (ws_size >= WBF_BYTES + XS_BYTES);

    if (fast) {
        unsigned short* Wbf  = (unsigned short*)d_ws;
        unsigned short* xsbf = (unsigned short*)((char*)d_ws + WBF_BYTES);
        k_wconv<<<512, 256, 0, stream>>>(Wq, Wk, Wbf);
        k_xpose<<<4096, 256, 0, stream>>>(x, xsbf);
        k_attn<true><<<P_TOTAL / 2, 512, 0, stream>>>(x, Wbf, xsbf, Wq, Wk, bq, bk, Wl, bl, out);
    } else {
        k_attn<false><<<P_TOTAL / 2, 512, 0, stream>>>(x, nullptr, nullptr, Wq, Wk, bq, bk, Wl, bl, out);
    }
}